// Round 4
// baseline (345.759 us; speedup 1.0000x reference)
//
#include <hip/hip_runtime.h>
#include <cstdint>
#include <cstddef>

// Binarized basic block on MI355X.
// |acc| <= 9*128 = 1152 < THRESH=8000 -> the per-partial-sum clip never binds
// -> both convs are exact int convolutions of sign() values. int8 implicit
// GEMM via mfma_i32_16x16x64_i8; float ops bit-exact vs numpy fp32.
//
// R13 (on R12 base): FEWER, FATTER WAVES.
//  R12 post-mortem: pinned ping-pong landed (traffic back to ideal) but wall
//  unchanged -> prefetch distance falsified as bottleneck. Both phases ~101us
//  at wildly different HBM traffic -> K-loop latency wall: at 2 waves/SIMD
//  each wave issues only 16 MFMAs (326 cyc) of blanket per step; both waves
//  run the same schedule and stall together ~3800 cyc/step.
//  -> 4 waves/block (256 thr), wave = 64 rows x 128 O (RG=4). Same per-CU
//     work (128 MFMA/step), but 32 contiguous MFMAs per wave per step
//     (653 cyc slack >= all warm-latency classes), half the ds_read load,
//     1 wave/SIMD with reg cap 512 (acc 128 + pingpong 96 + addr ~30).
//  Discriminator: R10 (more waves, less slack) hurt; R13 = fewer waves,
//  more slack. If unchanged -> per-CU servicing throughput is the wall.

typedef int      v4i __attribute__((ext_vector_type(4)));
typedef float    v4f __attribute__((ext_vector_type(4)));
typedef unsigned int v2u __attribute__((ext_vector_type(2)));

constexpr int B = 64, C = 128, H = 56, W = 56;
constexpr int HP = H + 2, WP = W + 2;      // zero-padded spatial
constexpr int PIX = H * W;                 // 3136
constexpr int M = B * H * W;               // 200704 = 784 * 256
constexpr int NTILES = M / 256;            // 784 tiles of 256 rows
constexpr int TPX = NTILES / 8;            // 98 tiles per XCD

// workspace layout (bytes)
constexpr size_t XS_BYTES = (size_t)B * HP * WP * C;   // 27,557,888
constexpr size_t XS1_OFF = 0;
constexpr size_t XS2_OFF = XS_BYTES;
constexpr size_t WF_BYTES = 18 * 8192;                 // 147,456
constexpr size_t WF1_OFF = 2 * XS_BYTES;
constexpr size_t WF2_OFF = WF1_OFF + WF_BYTES;
constexpr size_t BNP_OFF = WF2_OFF + WF_BYTES;         // 4*128 floats

// ---------------------------------------------------------------------------
// Zero only the padded halos of xs1/xs2. 256 blocks: 4 per image.
__global__ __launch_bounds__(256) void zero_halo(int8_t* __restrict__ xs1,
                                                 int8_t* __restrict__ xs2) {
    int b = blockIdx.x >> 2;
    int q = blockIdx.x & 3;
    int t = q * 256 + threadIdx.x;           // 0..1023
    size_t ib = (size_t)b * HP * WP * C;
#pragma unroll
    for (int a = 0; a < 2; ++a) {
        uint32_t* p = (uint32_t*)((a ? xs2 : xs1) + ib);
        const int ROWD = WP * C / 4;             // 1856 dwords per padded row
        for (int i = t; i < ROWD; i += 1024) {
            p[i] = 0;
            p[(HP - 1) * ROWD + i] = 0;
        }
        for (int i = t; i < 56 * 2 * 32; i += 1024) {
            int r = i >> 6;
            int side = (i >> 5) & 1;
            int j = i & 31;
            p[((r + 1) * WP + side * (WP - 1)) * (C / 4) + j] = 0;
        }
    }
}

// ---------------------------------------------------------------------------
// sign(x) -> padded NHWC int8 via LDS transpose (16 B/lane full-line stores).
__global__ __launch_bounds__(256) void prep_x(const float* __restrict__ x,
                                              int8_t* __restrict__ xs) {
    __shared__ uint32_t tl[256 * 33];
    int t = threadIdx.x;
    int m = blockIdx.x * 256 + t;
    int b_ = m / PIX, hw = m % PIX;
    const float* xp = x + (size_t)b_ * C * PIX + hw;
#pragma unroll
    for (int c4 = 0; c4 < 32; ++c4) {
        uint32_t v = 0;
#pragma unroll
        for (int j = 0; j < 4; ++j) {
            float f = __builtin_nontemporal_load(xp + (size_t)(c4 * 4 + j) * PIX);
            v |= ((uint32_t)(uint8_t)(int8_t)((f > 0.f) - (f < 0.f))) << (8 * j);
        }
        tl[t * 33 + c4] = v;
    }
    __syncthreads();
    int pl = t >> 3, co = t & 7;
#pragma unroll
    for (int pass = 0; pass < 8; ++pass) {
        int p = pass * 32 + pl;
        int mg = blockIdx.x * 256 + p;
        int b2 = mg / PIX, hw2 = mg % PIX, h2 = hw2 / W, w2 = hw2 % W;
        size_t ob = ((size_t)(b2 * HP + h2 + 1) * WP + (w2 + 1)) * C + co * 16;
        v4i val;
#pragma unroll
        for (int k = 0; k < 4; ++k) val[k] = (int)tl[p * 33 + co * 4 + k];
        *(v4i*)(xs + ob) = val;
    }
}

// ---------------------------------------------------------------------------
// Binarize weights into MFMA B-fragment order, slot = r*6 + kh*3 + s, with
// o = (lane&15)*8 + n (lane-contiguous O). BN tables exactly numpy fp32.
__global__ __launch_bounds__(256) void prep_w(
    const float* __restrict__ w1, const float* __restrict__ w2,
    const float* __restrict__ g1, const float* __restrict__ be1,
    const float* __restrict__ mu1, const float* __restrict__ va1,
    const float* __restrict__ g2, const float* __restrict__ be2,
    const float* __restrict__ mu2, const float* __restrict__ va2,
    int8_t* __restrict__ wf1, int8_t* __restrict__ wf2,
    float* __restrict__ bnp) {
    int t = blockIdx.x * 256 + threadIdx.x;
    if (t < 256) {
        int o = t & 127;
        if (t < 128) {
            float inv = g1[o] / sqrtf(va1[o] + 1e-5f);
            bnp[o]       = inv;
            bnp[128 + o] = __fsub_rn(be1[o], __fmul_rn(mu1[o], inv));
        } else {
            float inv = g2[o] / sqrtf(va2[o] + 1e-5f);
            bnp[256 + o] = inv;
            bnp[384 + o] = __fsub_rn(be2[o], __fmul_rn(mu2[o], inv));
        }
    }
    if (t >= 2 * 18 * 8 * 64) return;
    int lane = t & 63;
    int nsub = (t >> 6) & 7;
    int kh   = (t >> 9) & 1;
    int tap  = (t >> 10) % 9;
    int which = (t >> 10) / 9;
    const float* w = which ? w2 : w1;
    int8_t* wf = which ? wf2 : wf1;
    int o = (lane & 15) * 8 + nsub;
    int cbase = kh * 64 + (lane >> 4) * 16;
    int r = tap / 3, s = tap % 3;
    int slot = r * 6 + kh * 3 + s;           // (r, kh, s) step order
    int8_t frag[16];
#pragma unroll
    for (int j = 0; j < 16; ++j) {
        float f = w[((size_t)(o * C + cbase + j) * 3 + r) * 3 + s];
        frag[j] = (int8_t)((f > 0.f) - (f < 0.f));
    }
    *(v4i*)(wf + (size_t)((slot * 8 + nsub) * 64 + lane) * 16) =
        *(const v4i*)frag;
}

// ---------------------------------------------------------------------------
// One tile's worth of conv for one wave: RG row-groups x all 128 O.
// Ping-pong pipeline PINNED with sched_barrier(0): prefetch(s+1) must be
// issued before MFMA(s); compiler emits counted waits for the old set only.
template <int PHASE, int RG>
__device__ __forceinline__ void do_tile(
    int mwave, const int8_t* __restrict__ xs, const int8_t* wlds,
    const float* binv, const float* btt, int lane, int quad, int l15,
    const float* __restrict__ xres, int8_t* __restrict__ xs_next,
    float* __restrict__ out)
{
    int abase[RG];
#pragma unroll
    for (int rg = 0; rg < RG; ++rg) {
        int ma = mwave + rg * 16 + l15;
        int wa = ma % W; int ta = ma / W; int ha = ta % H; int ba = ta / H;
        abase[rg] = ((ba * HP + ha) * WP + wa) * C + quad * 16;
    }
    int lidx = lane << 4;

    v4i acc[RG][8];
#pragma unroll
    for (int rg = 0; rg < RG; ++rg)
#pragma unroll
        for (int n = 0; n < 8; ++n) acc[rg][n] = (v4i)0;

    v4i a0[RG], a1[RG], bf0[8], bf1[8];
    // prologue: set0 <- step 0 (aoff = 0, slot 0)
#pragma unroll
    for (int rg = 0; rg < RG; ++rg) a0[rg] = *(const v4i*)(xs + abase[rg]);
#pragma unroll
    for (int n = 0; n < 8; ++n)
        bf0[n] = *(const v4i*)(wlds + n * 1024 + lidx);
    __builtin_amdgcn_sched_barrier(0);

    const int8_t* wl = wlds;                 // slot base for this r
    int aoffr = 0;                           // r * WP * C
#pragma unroll 1
    for (int r3 = 0; r3 < 3; ++r3) {
        // 6 fully-unrolled substeps kk = kh*3 + s; step st = r3*6 + kk.
#pragma unroll
        for (int kk = 0; kk < 6; ++kk) {
            const bool last = (r3 == 2) && (kk == 5);
            if (!last) {
                // prefetch step st+1 into the other set. Compile-time offsets:
                // kk<5: kh=(kk+1)/3, s=(kk+1)%3 of same r; kk==5: next r, kh=s=0.
                const int nkh = (kk + 1 < 6) ? ((kk + 1) / 3) : 0;
                const int ns  = (kk + 1 < 6) ? ((kk + 1) % 3) : 0;
                const int rbump = (kk + 1 < 6) ? 0 : WP * C;
                int naoff = aoffr + rbump + nkh * 64 + ns * C;
                const int8_t* lb = wl + (kk + 1) * 8192;   // slot st+1
                if (((kk + 1) & 1) == 0) {
#pragma unroll
                    for (int rg = 0; rg < RG; ++rg)
                        a0[rg] = *(const v4i*)(xs + abase[rg] + naoff);
#pragma unroll
                    for (int n = 0; n < 8; ++n)
                        bf0[n] = *(const v4i*)(lb + n * 1024 + lidx);
                } else {
#pragma unroll
                    for (int rg = 0; rg < RG; ++rg)
                        a1[rg] = *(const v4i*)(xs + abase[rg] + naoff);
#pragma unroll
                    for (int n = 0; n < 8; ++n)
                        bf1[n] = *(const v4i*)(lb + n * 1024 + lidx);
                }
            }
            // Fence: loads above may not sink below; MFMAs may not hoist above.
            __builtin_amdgcn_sched_barrier(0);
            __builtin_amdgcn_s_setprio(1);
            if ((kk & 1) == 0) {
#pragma unroll
                for (int n = 0; n < 8; ++n)
#pragma unroll
                    for (int rg = 0; rg < RG; ++rg)
                        acc[rg][n] = __builtin_amdgcn_mfma_i32_16x16x64_i8(
                            a0[rg], bf0[n], acc[rg][n], 0, 0, 0);
            } else {
#pragma unroll
                for (int n = 0; n < 8; ++n)
#pragma unroll
                    for (int rg = 0; rg < RG; ++rg)
                        acc[rg][n] = __builtin_amdgcn_mfma_i32_16x16x64_i8(
                            a1[rg], bf1[n], acc[rg][n], 0, 0, 0);
            }
            __builtin_amdgcn_s_setprio(0);
            __builtin_amdgcn_sched_barrier(0);
        }
        aoffr += WP * C;
        wl += 6 * 8192;
    }

    // Epilogue. D layout: col = l15 (-> o = l15*8 + n), row = quad*4 + i.
#pragma unroll
    for (int rg = 0; rg < RG; ++rg) {
        int m0 = mwave + rg * 16 + quad * 4;         // multiple of 4; W%4==0
        int w0 = m0 % W; int t0 = m0 / W; int h0 = t0 % H; int b0 = t0 / H;
        if (PHASE == 1) {
            int base = ((b0 * HP + h0 + 1) * WP + (w0 + 1)) * C + l15 * 8;
#pragma unroll
            for (int i = 0; i < 4; ++i) {
                uint32_t lo = 0, hi = 0;
#pragma unroll
                for (int n = 0; n < 8; ++n) {
                    float y = __fadd_rn(__fmul_rn((float)acc[rg][n][i], binv[n]), btt[n]);
                    uint32_t sb = (uint8_t)(int8_t)((y > 0.f) - (y < 0.f));
                    if (n < 4) lo |= sb << (8 * n);
                    else       hi |= sb << (8 * (n - 4));
                }
                v2u pk; pk[0] = lo; pk[1] = hi;
                *(v2u*)(xs_next + base + i * C) = pk;
            }
        } else {
            int pixb = b0 * C * PIX + h0 * W + w0;
#pragma unroll
            for (int n = 0; n < 8; ++n) {
                int idx = pixb + (l15 * 8 + n) * PIX;
                v4f r = __builtin_nontemporal_load((const v4f*)(xres + idx));
                v4f z;
#pragma unroll
                for (int i = 0; i < 4; ++i) {
                    float y = __fadd_rn(__fmul_rn((float)acc[rg][n][i], binv[n]), btt[n]);
                    float v = __fadd_rn(y, r[i]);
                    z[i] = fminf(fmaxf(v, -1.f), 1.f);
                }
                __builtin_nontemporal_store(z, (v4f*)(out + idx));
            }
        }
    }
}

// ---------------------------------------------------------------------------
// Persistent binary conv. Grid = 256 blocks (1/CU, LDS-limited), 256 thr =
// 4 waves (1/SIMD). Wave = 64 rows x 128 O (acc[4][8], 32 MFMA/step).
// Schedule per XCD (xcd = bid&7, 32 blocks): 3 exact rounds over tiles
// [xcd*98, xcd*98+96), then the 2 leftover tiles as 4 half-tiles (RG=2,
// 32 rows/wave) on blocks local<4 -> wall 3.5 rounds.
template <int PHASE>
__global__ __launch_bounds__(256, 1) void conv_bin(
    const int8_t* __restrict__ xs,
    const int8_t* __restrict__ wf,
    const float* __restrict__ bnp,
    const float* __restrict__ xres,
    int8_t* __restrict__ xs_next,
    float* __restrict__ out)
{
    __shared__ int8_t wlds[18 * 8192];       // 147,456 B
    int t = threadIdx.x, lane = t & 63, wv = t >> 6;   // wv 0..3
    int quad = lane >> 4, l15 = lane & 15;

    // one-time weight staging
    {
        const v4i* g = (const v4i*)wf;
        v4i* l = (v4i*)wlds;
        for (int i = t; i < 18 * 512; i += 256) l[i] = g[i];
    }
    float binv[8], btt[8];
    {
        int o0 = (PHASE == 1 ? 0 : 256) + l15 * 8;
        int o1 = (PHASE == 1 ? 128 : 384) + l15 * 8;
#pragma unroll
        for (int n = 0; n < 8; ++n) { binv[n] = bnp[o0 + n]; btt[n] = bnp[o1 + n]; }
    }
    __syncthreads();

    int xcd = blockIdx.x & 7, local = blockIdx.x >> 3;   // 32 blocks per XCD
#pragma unroll 1
    for (int tloc = local; tloc < 96; tloc += 32) {      // exactly 3 rounds
        int tile = xcd * TPX + tloc;
        do_tile<PHASE, 4>(tile * 256 + wv * 64, xs, wlds, binv, btt,
                          lane, quad, l15, xres, xs_next, out);
    }
    if (local < 4) {                                     // tail: 2 tiles/XCD
        int tile = xcd * TPX + 96 + (local >> 1);
        int mw = tile * 256 + (local & 1) * 128 + wv * 32;
        do_tile<PHASE, 2>(mw, xs, wlds, binv, btt,
                          lane, quad, l15, xres, xs_next, out);
    }
}

// ---------------------------------------------------------------------------
extern "C" void kernel_launch(void* const* d_in, const int* in_sizes, int n_in,
                              void* d_out, int out_size, void* d_ws, size_t ws_size,
                              hipStream_t stream) {
    const float* x   = (const float*)d_in[0];
    const float* w1  = (const float*)d_in[1];
    const float* w2  = (const float*)d_in[2];
    const float* g1  = (const float*)d_in[3];
    const float* be1 = (const float*)d_in[4];
    const float* mu1 = (const float*)d_in[5];
    const float* va1 = (const float*)d_in[6];
    const float* g2  = (const float*)d_in[7];
    const float* be2 = (const float*)d_in[8];
    const float* mu2 = (const float*)d_in[9];
    const float* va2 = (const float*)d_in[10];

    int8_t* ws  = (int8_t*)d_ws;
    int8_t* xs1 = ws + XS1_OFF;
    int8_t* xs2 = ws + XS2_OFF;
    int8_t* wf1 = ws + WF1_OFF;
    int8_t* wf2 = ws + WF2_OFF;
    float*  bnp = (float*)(ws + BNP_OFF);

    zero_halo<<<256, 256, 0, stream>>>(xs1, xs2);
    prep_x<<<M / 256, 256, 0, stream>>>(x, xs1);
    prep_w<<<(2 * 18 * 8 * 64 + 255) / 256, 256, 0, stream>>>(
        w1, w2, g1, be1, mu1, va1, g2, be2, mu2, va2, wf1, wf2, bnp);

    conv_bin<1><<<256, 256, 0, stream>>>(xs1, wf1, bnp, nullptr, xs2, nullptr);
    conv_bin<2><<<256, 256, 0, stream>>>(xs2, wf2, bnp, x, nullptr, (float*)d_out);
}

// Round 5
// 329.611 us; speedup vs baseline: 1.0490x; 1.0490x over previous
//
#include <hip/hip_runtime.h>
#include <cstdint>
#include <cstddef>

// Binarized basic block on MI355X.
// |acc| <= 9*128 = 1152 < THRESH=8000 -> the per-partial-sum clip never binds
// -> both convs are exact int convolutions of sign() values. int8 implicit
// GEMM via mfma_i32_16x16x64_i8; float ops bit-exact vs numpy fp32.
//
// R14 (on R12 base; K-loop untouched): KILL THE IDLE TAIL + FUSE PREPS.
//  R13 falsified slack/occupancy as the K-loop lever (VGPR=240 real pipeline,
//  slower). Re-read of counters: all top-5 dispatches are the SAME launch
//  position (ids = same mod 18) -> we only ever saw one conv; its F/W match
//  ideal. Occupancy 18% vs 25% resident = the 4th round runs 4 blocks/XCD
//  (RG=1 half-tiles) while 87% of CUs idle; latency-bound => tail round costs
//  a FULL round (~25us/conv).
//  -> Round-3 merge: leftover 512 rows/XCD ride as a 3rd row-group (RG=3) on
//     the 32 waves of blocks local<4; extra 8 MFMA/step is free under the
//     latency wall. Wall: 4 rounds -> 3.
//  -> prep_all: zero_halo + prep_w + bnp fused into prep_x's 784-block grid
//     (launches 5 -> 3; prep_w's scattered reads hidden under the big grid).

typedef int      v4i __attribute__((ext_vector_type(4)));
typedef float    v4f __attribute__((ext_vector_type(4)));
typedef unsigned int v2u __attribute__((ext_vector_type(2)));

constexpr int B = 64, C = 128, H = 56, W = 56;
constexpr int HP = H + 2, WP = W + 2;      // zero-padded spatial
constexpr int PIX = H * W;                 // 3136
constexpr int M = B * H * W;               // 200704 = 784 * 256
constexpr int NTILES = M / 256;            // 784 tiles of 256 rows
constexpr int TPX = NTILES / 8;            // 98 tiles per XCD

// workspace layout (bytes)
constexpr size_t XS_BYTES = (size_t)B * HP * WP * C;   // 27,557,888
constexpr size_t XS1_OFF = 0;
constexpr size_t XS2_OFF = XS_BYTES;
constexpr size_t WF_BYTES = 18 * 8192;                 // 147,456
constexpr size_t WF1_OFF = 2 * XS_BYTES;
constexpr size_t WF2_OFF = WF1_OFF + WF_BYTES;
constexpr size_t BNP_OFF = WF2_OFF + WF_BYTES;         // 4*128 floats

// ---------------------------------------------------------------------------
// Fused prep: sign(x) -> padded NHWC int8 (LDS transpose, full-line stores),
// + weight binarize/layout + BN tables + halo zeroing, all in one 784-block
// grid.
__global__ __launch_bounds__(256) void prep_all(
    const float* __restrict__ x,
    const float* __restrict__ w1, const float* __restrict__ w2,
    const float* __restrict__ g1, const float* __restrict__ be1,
    const float* __restrict__ mu1, const float* __restrict__ va1,
    const float* __restrict__ g2, const float* __restrict__ be2,
    const float* __restrict__ mu2, const float* __restrict__ va2,
    int8_t* __restrict__ xs1, int8_t* __restrict__ xs2,
    int8_t* __restrict__ wf1, int8_t* __restrict__ wf2,
    float* __restrict__ bnp)
{
    __shared__ uint32_t tl[256 * 33];
    int t = threadIdx.x;
    int tg = blockIdx.x * 256 + t;

    // ---- part A: x -> sign -> xs1 interior (original prep_x) ----
    {
        int m = tg;
        int b_ = m / PIX, hw = m % PIX;
        const float* xp = x + (size_t)b_ * C * PIX + hw;
#pragma unroll
        for (int c4 = 0; c4 < 32; ++c4) {
            uint32_t v = 0;
#pragma unroll
            for (int j = 0; j < 4; ++j) {
                float f = __builtin_nontemporal_load(xp + (size_t)(c4 * 4 + j) * PIX);
                v |= ((uint32_t)(uint8_t)(int8_t)((f > 0.f) - (f < 0.f))) << (8 * j);
            }
            tl[t * 33 + c4] = v;
        }
        __syncthreads();
        int pl = t >> 3, co = t & 7;
#pragma unroll
        for (int pass = 0; pass < 8; ++pass) {
            int p = pass * 32 + pl;
            int mg = blockIdx.x * 256 + p;
            int b2 = mg / PIX, hw2 = mg % PIX, h2 = hw2 / W, w2 = hw2 % W;
            size_t ob = ((size_t)(b2 * HP + h2 + 1) * WP + (w2 + 1)) * C + co * 16;
            v4i val;
#pragma unroll
            for (int k = 0; k < 4; ++k) val[k] = (int)tl[p * 33 + co * 4 + k];
            *(v4i*)(xs1 + ob) = val;
        }
    }

    // ---- part B: BN tables (threads 0..255 of the grid) ----
    if (tg < 256) {
        int o = tg & 127;
        if (tg < 128) {
            float inv = g1[o] / sqrtf(va1[o] + 1e-5f);
            bnp[o]       = inv;
            bnp[128 + o] = __fsub_rn(be1[o], __fmul_rn(mu1[o], inv));
        } else {
            float inv = g2[o] / sqrtf(va2[o] + 1e-5f);
            bnp[256 + o] = inv;
            bnp[384 + o] = __fsub_rn(be2[o], __fmul_rn(mu2[o], inv));
        }
    }

    // ---- part C: weight binarize into MFMA B-frag order ----
    // slot = r*6 + kh*3 + s; o = (lane&15)*8 + nsub (lane-contiguous O).
    if (tg < 2 * 18 * 8 * 64) {
        int lane = tg & 63;
        int nsub = (tg >> 6) & 7;
        int kh   = (tg >> 9) & 1;
        int tap  = (tg >> 10) % 9;
        int which = (tg >> 10) / 9;
        const float* w = which ? w2 : w1;
        int8_t* wf = which ? wf2 : wf1;
        int o = (lane & 15) * 8 + nsub;
        int cbase = kh * 64 + (lane >> 4) * 16;
        int r = tap / 3, s = tap % 3;
        int slot = r * 6 + kh * 3 + s;
        int8_t frag[16];
#pragma unroll
        for (int j = 0; j < 16; ++j) {
            float f = w[((size_t)(o * C + cbase + j) * 3 + r) * 3 + s];
            frag[j] = (int8_t)((f > 0.f) - (f < 0.f));
        }
        *(v4i*)(wf + (size_t)((slot * 8 + nsub) * 64 + lane) * 16) =
            *(const v4i*)frag;
    }

    // ---- part D: halo zeroing of xs1 & xs2, grid-strided ----
    // per array per image: top row (1856 dw) + bottom row (1856) + sides
    // (56 rows x 2 sides x 32 dw = 3584) = 7296 dwords.
    {
        constexpr int ROWD = WP * C / 4;                 // 1856
        constexpr int HPI  = 2 * ROWD + 56 * 2 * 32;     // 7296
        constexpr int PERA = B * HPI;                    // 466,944
        constexpr int TOT  = 2 * PERA;                   // 933,888
        for (int i = tg; i < TOT; i += M) {
            int a   = i / PERA;
            int rem = i - a * PERA;
            int b_  = rem / HPI;
            int s   = rem - b_ * HPI;
            uint32_t* p = (uint32_t*)((a ? xs2 : xs1) + (size_t)b_ * HP * WP * C);
            if (s < ROWD) {
                p[s] = 0;
            } else if (s < 2 * ROWD) {
                p[(HP - 1) * ROWD + (s - ROWD)] = 0;
            } else {
                int j = s - 2 * ROWD;
                int r = j >> 6, side = (j >> 5) & 1, k = j & 31;
                p[((r + 1) * WP + side * (WP - 1)) * (C / 4) + k] = 0;
            }
        }
    }
}

// ---------------------------------------------------------------------------
// One tile's worth of conv for one wave: RG 16-row groups (arbitrary row
// starts via mrows[]) x all 128 O. Ping-pong pipeline PINNED with
// sched_barrier(0): prefetch(s+1) issued before MFMA(s); counted waits only.
template <int PHASE, int RG>
__device__ __forceinline__ void do_tile(
    const int (&mrows)[RG], const int8_t* __restrict__ xs, const int8_t* wlds,
    const float* binv, const float* btt, int lane, int quad, int l15,
    const float* __restrict__ xres, int8_t* __restrict__ xs_next,
    float* __restrict__ out)
{
    int abase[RG];
#pragma unroll
    for (int rg = 0; rg < RG; ++rg) {
        int ma = mrows[rg] + l15;
        int wa = ma % W; int ta = ma / W; int ha = ta % H; int ba = ta / H;
        abase[rg] = ((ba * HP + ha) * WP + wa) * C + quad * 16;
    }
    int lidx = lane << 4;

    v4i acc[RG][8];
#pragma unroll
    for (int rg = 0; rg < RG; ++rg)
#pragma unroll
        for (int n = 0; n < 8; ++n) acc[rg][n] = (v4i)0;

    v4i a0[RG], a1[RG], bf0[8], bf1[8];
    // prologue: set0 <- step 0 (aoff = 0, slot 0)
#pragma unroll
    for (int rg = 0; rg < RG; ++rg) a0[rg] = *(const v4i*)(xs + abase[rg]);
#pragma unroll
    for (int n = 0; n < 8; ++n)
        bf0[n] = *(const v4i*)(wlds + n * 1024 + lidx);
    __builtin_amdgcn_sched_barrier(0);

    const int8_t* wl = wlds;                 // slot base for this r
    int aoffr = 0;                           // r * WP * C
#pragma unroll 1
    for (int r3 = 0; r3 < 3; ++r3) {
        // 6 fully-unrolled substeps kk = kh*3 + s; step st = r3*6 + kk.
#pragma unroll
        for (int kk = 0; kk < 6; ++kk) {
            const bool last = (r3 == 2) && (kk == 5);
            if (!last) {
                // prefetch step st+1 into the other set. Compile-time offsets:
                // kk<5: kh=(kk+1)/3, s=(kk+1)%3 of same r; kk==5: next r, kh=s=0.
                const int nkh = (kk + 1 < 6) ? ((kk + 1) / 3) : 0;
                const int ns  = (kk + 1 < 6) ? ((kk + 1) % 3) : 0;
                const int rbump = (kk + 1 < 6) ? 0 : WP * C;
                int naoff = aoffr + rbump + nkh * 64 + ns * C;
                const int8_t* lb = wl + (kk + 1) * 8192;   // slot st+1
                if (((kk + 1) & 1) == 0) {
#pragma unroll
                    for (int rg = 0; rg < RG; ++rg)
                        a0[rg] = *(const v4i*)(xs + abase[rg] + naoff);
#pragma unroll
                    for (int n = 0; n < 8; ++n)
                        bf0[n] = *(const v4i*)(lb + n * 1024 + lidx);
                } else {
#pragma unroll
                    for (int rg = 0; rg < RG; ++rg)
                        a1[rg] = *(const v4i*)(xs + abase[rg] + naoff);
#pragma unroll
                    for (int n = 0; n < 8; ++n)
                        bf1[n] = *(const v4i*)(lb + n * 1024 + lidx);
                }
            }
            // Fence: loads above may not sink below; MFMAs may not hoist above.
            __builtin_amdgcn_sched_barrier(0);
            __builtin_amdgcn_s_setprio(1);
            if ((kk & 1) == 0) {
#pragma unroll
                for (int n = 0; n < 8; ++n)
#pragma unroll
                    for (int rg = 0; rg < RG; ++rg)
                        acc[rg][n] = __builtin_amdgcn_mfma_i32_16x16x64_i8(
                            a0[rg], bf0[n], acc[rg][n], 0, 0, 0);
            } else {
#pragma unroll
                for (int n = 0; n < 8; ++n)
#pragma unroll
                    for (int rg = 0; rg < RG; ++rg)
                        acc[rg][n] = __builtin_amdgcn_mfma_i32_16x16x64_i8(
                            a1[rg], bf1[n], acc[rg][n], 0, 0, 0);
            }
            __builtin_amdgcn_s_setprio(0);
            __builtin_amdgcn_sched_barrier(0);
        }
        aoffr += WP * C;
        wl += 6 * 8192;
    }

    // Epilogue. D layout: col = l15 (-> o = l15*8 + n), row = quad*4 + i.
#pragma unroll
    for (int rg = 0; rg < RG; ++rg) {
        int m0 = mrows[rg] + quad * 4;                // multiple of 4; W%4==0
        int w0 = m0 % W; int t0 = m0 / W; int h0 = t0 % H; int b0 = t0 / H;
        if (PHASE == 1) {
            int base = ((b0 * HP + h0 + 1) * WP + (w0 + 1)) * C + l15 * 8;
#pragma unroll
            for (int i = 0; i < 4; ++i) {
                uint32_t lo = 0, hi = 0;
#pragma unroll
                for (int n = 0; n < 8; ++n) {
                    float y = __fadd_rn(__fmul_rn((float)acc[rg][n][i], binv[n]), btt[n]);
                    uint32_t sb = (uint8_t)(int8_t)((y > 0.f) - (y < 0.f));
                    if (n < 4) lo |= sb << (8 * n);
                    else       hi |= sb << (8 * (n - 4));
                }
                v2u pk; pk[0] = lo; pk[1] = hi;
                *(v2u*)(xs_next + base + i * C) = pk;
            }
        } else {
            int pixb = b0 * C * PIX + h0 * W + w0;
#pragma unroll
            for (int n = 0; n < 8; ++n) {
                int idx = pixb + (l15 * 8 + n) * PIX;
                v4f r = __builtin_nontemporal_load((const v4f*)(xres + idx));
                v4f z;
#pragma unroll
                for (int i = 0; i < 4; ++i) {
                    float y = __fadd_rn(__fmul_rn((float)acc[rg][n][i], binv[n]), btt[n]);
                    float v = __fadd_rn(y, r[i]);
                    z[i] = fminf(fmaxf(v, -1.f), 1.f);
                }
                __builtin_nontemporal_store(z, (v4f*)(out + idx));
            }
        }
    }
}

// ---------------------------------------------------------------------------
// Persistent binary conv. Grid = 256 blocks (1/CU, LDS-limited), 512 thr =
// 8 waves (2/SIMD). Wave = 32 rows x 128 O (acc[2][8]).
// Schedule per XCD (xcd = bid&7, 32 blocks): EXACTLY 3 rounds. Rounds 0-1:
// RG=2 tiles. Round 2: blocks local<4 run RG=3 (their tile + one 16-row
// group of the 2 leftover tiles; 32 waves x 16 rows = 512 = 2 tiles).
// Extra 8 MFMA/step rides free under the latency wall -> no 4th round.
template <int PHASE>
__global__ __launch_bounds__(512, 1) void conv_bin(
    const int8_t* __restrict__ xs,
    const int8_t* __restrict__ wf,
    const float* __restrict__ bnp,
    const float* __restrict__ xres,
    int8_t* __restrict__ xs_next,
    float* __restrict__ out)
{
    __shared__ int8_t wlds[18 * 8192];       // 147,456 B
    int t = threadIdx.x, lane = t & 63, wv = t >> 6;
    int quad = lane >> 4, l15 = lane & 15;

    // one-time weight staging
    {
        const v4i* g = (const v4i*)wf;
        v4i* l = (v4i*)wlds;
        for (int i = t; i < 18 * 512; i += 512) l[i] = g[i];
    }
    float binv[8], btt[8];
    {
        int o0 = (PHASE == 1 ? 0 : 256) + l15 * 8;
        int o1 = (PHASE == 1 ? 128 : 384) + l15 * 8;
#pragma unroll
        for (int n = 0; n < 8; ++n) { binv[n] = bnp[o0 + n]; btt[n] = bnp[o1 + n]; }
    }
    __syncthreads();

    int xcd = blockIdx.x & 7, local = blockIdx.x >> 3;   // 32 blocks per XCD

    // rounds 0,1: plain RG=2
#pragma unroll 1
    for (int rd = 0; rd < 2; ++rd) {
        int tile = xcd * TPX + local + rd * 32;
        int mw = tile * 256 + wv * 32;
        int mrows2[2] = { mw, mw + 16 };
        do_tile<PHASE, 2>(mrows2, xs, wlds, binv, btt,
                          lane, quad, l15, xres, xs_next, out);
    }
    // round 2: blocks local<4 carry the leftover rows as a 3rd row-group
    {
        int tile = xcd * TPX + local + 64;
        int mw = tile * 256 + wv * 32;
        if (local < 4) {
            int tailrow = (xcd * TPX + 96) * 256 + (local * 8 + wv) * 16;
            int mrows3[3] = { mw, mw + 16, tailrow };
            do_tile<PHASE, 3>(mrows3, xs, wlds, binv, btt,
                              lane, quad, l15, xres, xs_next, out);
        } else {
            int mrows2[2] = { mw, mw + 16 };
            do_tile<PHASE, 2>(mrows2, xs, wlds, binv, btt,
                              lane, quad, l15, xres, xs_next, out);
        }
    }
}

// ---------------------------------------------------------------------------
extern "C" void kernel_launch(void* const* d_in, const int* in_sizes, int n_in,
                              void* d_out, int out_size, void* d_ws, size_t ws_size,
                              hipStream_t stream) {
    const float* x   = (const float*)d_in[0];
    const float* w1  = (const float*)d_in[1];
    const float* w2  = (const float*)d_in[2];
    const float* g1  = (const float*)d_in[3];
    const float* be1 = (const float*)d_in[4];
    const float* mu1 = (const float*)d_in[5];
    const float* va1 = (const float*)d_in[6];
    const float* g2  = (const float*)d_in[7];
    const float* be2 = (const float*)d_in[8];
    const float* mu2 = (const float*)d_in[9];
    const float* va2 = (const float*)d_in[10];

    int8_t* ws  = (int8_t*)d_ws;
    int8_t* xs1 = ws + XS1_OFF;
    int8_t* xs2 = ws + XS2_OFF;
    int8_t* wf1 = ws + WF1_OFF;
    int8_t* wf2 = ws + WF2_OFF;
    float*  bnp = (float*)(ws + BNP_OFF);

    prep_all<<<M / 256, 256, 0, stream>>>(
        x, w1, w2, g1, be1, mu1, va1, g2, be2, mu2, va2,
        xs1, xs2, wf1, wf2, bnp);

    conv_bin<1><<<256, 512, 0, stream>>>(xs1, wf1, bnp, nullptr, xs2, nullptr);
    conv_bin<2><<<256, 512, 0, stream>>>(xs2, wf2, bnp, x, nullptr, (float*)d_out);
}